// Round 4
// baseline (239.749 us; speedup 1.0000x reference)
//
#include <hip/hip_runtime.h>

typedef __bf16 bx8 __attribute__((ext_vector_type(8)));
typedef __bf16 bx4 __attribute__((ext_vector_type(4)));
typedef float  fx4 __attribute__((ext_vector_type(4)));
typedef unsigned long long u64;

#define B_   4
#define S_   2048
#define DIN  1024
#define DH   1024

#define MB ((size_t)1 << 20)
// workspace layout (bytes)
#define WS_A1 ((size_t)0)          // seq1 bf16, 16MB   (aliased by Pu later)
#define WS_A2 ((size_t)16*MB)      // seq2 bf16, 16MB   (aliased by Pu later)
#define WS_PU ((size_t)0)          // exp-scores bf16, 32MB (after QKV done)
#define WS_WQ ((size_t)32*MB)      // Wq bf16 2MB; after Q-proj reused as mask bitmask (2MB)
#define WS_BM WS_WQ
#define WS_WK ((size_t)34*MB)      // Wk,Wv contiguous => fused [Wk;Wv] N=2048
#define WS_WV ((size_t)36*MB)
#define WS_Q  ((size_t)38*MB)      // q bf16 [B*S, DH] 16MB
#define WS_K  ((size_t)54*MB)      // k bf16 [B*S, DH] 16MB
#define WS_VT ((size_t)70*MB)      // v^T bf16 [B, DH, S] 16MB
#define WS_CS ((size_t)86*MB)      // colsum fp32 [B, S] 32KB

// ---------------------------------------------------------------- cvt f32->bf16
__global__ void cvt_f32_bf16(const float* __restrict__ in, __bf16* __restrict__ out) {
  size_t i = (size_t)blockIdx.x * blockDim.x + threadIdx.x;
  fx4 lo = ((const fx4*)in)[2 * i];
  fx4 hi = ((const fx4*)in)[2 * i + 1];
  bx8 o;
#pragma unroll
  for (int j = 0; j < 4; j++) { o[j] = (__bf16)lo[j]; o[j + 4] = (__bf16)hi[j]; }
  ((bx8*)out)[i] = o;
}

// ---------------------------------------------------------------- pack int32 mask -> bits
__global__ void pack_mask(const int* __restrict__ m, u64* __restrict__ w) {
  // 256 thr = 4 waves; each wave: 8 iters x 64 ints -> 8 u64 words
  const int wid = threadIdx.x >> 6, lane = threadIdx.x & 63;
  const size_t base = ((size_t)blockIdx.x * 4 + wid) * 512;
#pragma unroll
  for (int i = 0; i < 8; i++) {
    int v = m[base + i * 64 + lane];
    u64 b = __ballot(v != 0);
    if (lane == 0) w[base / 64 + i] = b;
  }
}

// ---------------------------------------------------------------- 256x256 GEMM  C = A @ B^T
// BM=BN=256, BK=64, 512 thr = 8 waves (2 wr x 4 wc), per-wave 128x64, acc[8][4].
// LDS 128KB: buf*65536 + {A: [256][128B] at 0, B: [256][128B] at 32768}.
// Swizzle: lds colb = logical_colb ^ ((row&7)<<4); inverse folded into global src.
// 2 sync points per K-tile (free-run between): mid-barrier after ph1 protects
// cb-B reuse by B(t+2) staging; end vmcnt(4)+barrier retires {B(t+1),A(t+1)},
// keeps B(t+2)'s 4 loads in flight. Ledger identical to R3 (verified passing).

enum { EP_BF16 = 0, EP_KV = 1, EP_EXP = 2, EP_F32 = 3 };

#define GLD(gp, lp)                                                              \
  __builtin_amdgcn_global_load_lds(                                              \
      (const __attribute__((address_space(1))) void*)(const void*)(gp),          \
      (__attribute__((address_space(3))) void*)(void*)(lp), 16, 0, 0)

#define MIDBAR()                                 \
  do {                                           \
    asm volatile("" ::: "memory");               \
    __builtin_amdgcn_s_barrier();                \
    asm volatile("" ::: "memory");               \
  } while (0)

#define ENDSYNC()                                          \
  do {                                                     \
    asm volatile("s_waitcnt vmcnt(4)" ::: "memory");       \
    __builtin_amdgcn_s_barrier();                          \
    asm volatile("" ::: "memory");                         \
  } while (0)

#define MM(m, n, av, bv) \
  acc[m][n] = __builtin_amdgcn_mfma_f32_16x16x32_bf16(av, bv, acc[m][n], 0, 0, 0)
#define MFMA16(mA, mB) do {                                                       \
  MM(mA,0,a0k0,bk0n0); MM(mA,1,a0k0,bk0n1); MM(mA,2,a0k0,bk0n2); MM(mA,3,a0k0,bk0n3); \
  MM(mB,0,a1k0,bk0n0); MM(mB,1,a1k0,bk0n1); MM(mB,2,a1k0,bk0n2); MM(mB,3,a1k0,bk0n3); \
  MM(mA,0,a0k1,bk1n0); MM(mA,1,a0k1,bk1n1); MM(mA,2,a0k1,bk1n2); MM(mA,3,a0k1,bk1n3); \
  MM(mB,0,a1k1,bk1n0); MM(mB,1,a1k1,bk1n1); MM(mB,2,a1k1,bk1n2); MM(mB,3,a1k1,bk1n3); \
} while (0)

#define LDA_(buf, m, kk) (*(const bx8*)(aBase + (buf) * 65536 + (m) * 2048 + ((kk) ? c1s : c0s)))
#define LDB_(buf, n, kk) (*(const bx8*)(bBase + (buf) * 65536 + (n) * 2048 + ((kk) ? c1s : c0s)))
#define RD_A(cb, mA, mB)                             \
  a0k0 = LDA_(cb, mA, 0); a0k1 = LDA_(cb, mA, 1);    \
  a1k0 = LDA_(cb, mB, 0); a1k1 = LDA_(cb, mB, 1)

#define STAGE_A(kt, h, buf) do {                                                          \
  GLD(pA + (size_t)((h) * 128) * K + (kt),      smem + (buf) * 65536 + (h) * 16384 + tid * 16);        \
  GLD(pA + (size_t)((h) * 128 + 64) * K + (kt), smem + (buf) * 65536 + (h) * 16384 + 8192 + tid * 16); \
} while (0)
#define STAGE_B(kt, h, buf) do {                                                          \
  GLD(pB + (size_t)((h) * 128) * K + (kt),      smem + (buf) * 65536 + 32768 + (h) * 16384 + tid * 16);        \
  GLD(pB + (size_t)((h) * 128 + 64) * K + (kt), smem + (buf) * 65536 + 32768 + (h) * 16384 + 8192 + tid * 16); \
} while (0)

template <int EPI>
__global__ __launch_bounds__(512, 2) void gemm256(
    const __bf16* __restrict__ A, const __bf16* __restrict__ Bm,
    void* __restrict__ Cout, void* __restrict__ Cout2,
    const u64* __restrict__ MaskW, int N, int K, long sA, long sB) {
  extern __shared__ char smem[];
  const int bz = blockIdx.z;
  A  += (long)bz * sA;
  Bm += (long)bz * sB;
  const int brow = blockIdx.y * 256;
  const int bcol = blockIdx.x * 256;

  const int tid  = threadIdx.x;
  const int wid  = tid >> 6;
  const int lane = tid & 63;
  const int wr = wid >> 2;   // 0..1 -> rows wr*128
  const int wc = wid & 3;    // 0..3 -> cols wc*64

  fx4 acc[8][4] = {};

  // staging: thread covers lds flat tid*16 (+8192*i) per half; inverse swizzle on global col
  const int gcol = (((tid & 7) ^ ((tid >> 3) & 7)) << 3);  // elements
  const __bf16* pA = A  + (size_t)(brow + (tid >> 3)) * K + gcol;
  const __bf16* pB = Bm + (size_t)(bcol + (tid >> 3)) * K + gcol;

  // fragment read bases (read-side swizzle)
  const int frow = lane & 15;
  const int slot = (lane >> 4) << 4;
  const int c0s  = slot ^ ((frow & 7) << 4);
  const int c1s  = (64 + slot) ^ ((frow & 7) << 4);
  const char* aBase = smem + (wr * 128 + frow) * 128;
  const char* bBase = smem + 32768 + (wc * 64 + frow) * 128;

  // ---- prologue: tile0 fully + B halves of tile1; keep 4 loads in flight
  STAGE_A(0, 0, 0); STAGE_A(0, 1, 0);
  STAGE_B(0, 0, 0); STAGE_B(0, 1, 0);
  STAGE_B(64, 0, 1); STAGE_B(64, 1, 1);
  ENDSYNC();

  const int nt = K >> 6;
  bx8 a0k0, a0k1, a1k0, a1k1;
  bx8 bk0n0, bk0n1, bk0n2, bk0n3, bk1n0, bk1n1, bk1n2, bk1n3;

  for (int t = 0; t < nt; ++t) {
    const int cb = t & 1, nb = cb ^ 1;
    const int kA = (t + 1 < nt) ? (t + 1) * 64 : 0;  // junk when past end, never read
    const int kB = (t + 2 < nt) ? (t + 2) * 64 : 0;

    // ---- ph0: m0,m1 (12 ds_reads: 4 A + 8 B; B regs held all tile)
    RD_A(cb, 0, 1);
    bk0n0 = LDB_(cb, 0, 0); bk0n1 = LDB_(cb, 1, 0); bk0n2 = LDB_(cb, 2, 0); bk0n3 = LDB_(cb, 3, 0);
    bk1n0 = LDB_(cb, 0, 1); bk1n1 = LDB_(cb, 1, 1); bk1n2 = LDB_(cb, 2, 1); bk1n3 = LDB_(cb, 3, 1);
    STAGE_A(kA, 0, nb);
    __builtin_amdgcn_s_setprio(1); MFMA16(0, 1); __builtin_amdgcn_s_setprio(0);
    // ---- ph1: m2,m3
    RD_A(cb, 2, 3);
    STAGE_A(kA, 1, nb);
    __builtin_amdgcn_s_setprio(1); MFMA16(2, 3); __builtin_amdgcn_s_setprio(0);
    MIDBAR();   // all waves' ph0 B reads drained -> cb-B safe to overwrite
    // ---- ph2: m4,m5
    RD_A(cb, 4, 5);
    STAGE_B(kB, 0, cb);
    __builtin_amdgcn_s_setprio(1); MFMA16(4, 5); __builtin_amdgcn_s_setprio(0);
    // ---- ph3: m6,m7
    RD_A(cb, 6, 7);
    STAGE_B(kB, 1, cb);
    __builtin_amdgcn_s_setprio(1); MFMA16(6, 7); __builtin_amdgcn_s_setprio(0);
    ENDSYNC();  // retires {B(t+1), A(t+1)}; keeps B(t+2) (4 loads) in flight
  }

  // ---- epilogue: C/D layout col = lane&15, row = (lane>>4)*4 + j  [verified m89]
  const int r0 = wr * 128 + (lane >> 4) * 4;
  const int c0 = wc * 64 + (lane & 15);

  if (EPI == EP_BF16) {
    __bf16* C = (__bf16*)Cout;
#pragma unroll
    for (int m = 0; m < 8; m++) {
      int row = brow + r0 + m * 16;
#pragma unroll
      for (int n = 0; n < 4; n++) {
        int col = bcol + c0 + n * 16;
#pragma unroll
        for (int j = 0; j < 4; j++)
          C[(size_t)(row + j) * N + col] = (__bf16)acc[m][n][j];
      }
    }
  } else if (EPI == EP_KV) {
    // cols 0-1023 -> k [8192,1024]; cols 1024-2047 -> vT[b][col-1024][s]
    __bf16* Ck = (__bf16*)Cout;
    __bf16* Cv = (__bf16*)Cout2;
    if (bcol < 1024) {
#pragma unroll
      for (int m = 0; m < 8; m++) {
        int row = brow + r0 + m * 16;
#pragma unroll
        for (int n = 0; n < 4; n++) {
          int col = bcol + c0 + n * 16;
#pragma unroll
          for (int j = 0; j < 4; j++)
            Ck[(size_t)(row + j) * 1024 + col] = (__bf16)acc[m][n][j];
        }
      }
    } else {
#pragma unroll
      for (int m = 0; m < 8; m++) {
        int row  = brow + r0 + m * 16;
        size_t bb = (size_t)(row >> 11) << 21;  // batch * DH*S
        int sidx = row & 2047;
#pragma unroll
        for (int n = 0; n < 4; n++) {
          int col = bcol + c0 + n * 16 - 1024;
          bx4 tv;
#pragma unroll
          for (int j = 0; j < 4; j++) tv[j] = (__bf16)acc[m][n][j];
          *(bx4*)&Cv[bb + (size_t)col * S_ + sidx] = tv;
        }
      }
    }
  } else if (EPI == EP_EXP) {
    __bf16* C    = (__bf16*)Cout + (size_t)bz * ((size_t)S_ * S_);
    const u64* Wm = MaskW + (((size_t)bz * S_ * S_) >> 6);
    float* cs    = (float*)Cout2 + (size_t)bz * S_;
#pragma unroll
    for (int n = 0; n < 4; n++) {
      int col = bcol + c0 + n * 16;
      float csum = 0.f;
#pragma unroll
      for (int m = 0; m < 8; m++) {
        int row = brow + r0 + m * 16;
#pragma unroll
        for (int j = 0; j < 4; j++) {
          size_t idx = (size_t)(row + j) * S_ + col;
          bool mk = (Wm[idx >> 6] >> (idx & 63)) & 1;
          float p = mk ? 1.0f : __expf(acc[m][n][j] * 0.03125f);  // 1/sqrt(1024)
          csum += p;
          C[idx] = (__bf16)p;
        }
      }
      atomicAdd(&cs[col], csum);
    }
  } else {  // EP_F32
    float* C = (float*)Cout + (size_t)bz * ((size_t)S_ * DH);
#pragma unroll
    for (int m = 0; m < 8; m++) {
      int row = brow + r0 + m * 16;
#pragma unroll
      for (int n = 0; n < 4; n++) {
        int col = bcol + c0 + n * 16;
#pragma unroll
        for (int j = 0; j < 4; j++)
          C[(size_t)(row + j) * N + col] = acc[m][n][j];
      }
    }
  }
}

// ---------------------------------------------------------------- vT[b][h][k] /= colsum[b][k]
__global__ void scale_vt(__bf16* __restrict__ vT, const float* __restrict__ cs) {
  size_t i = (size_t)blockIdx.x * blockDim.x + threadIdx.x;
  size_t e = i * 8;
  int b = (int)(e >> 21);      // DH*S = 2^21 elems per batch
  int k = (int)(e & (S_ - 1)); // contiguous along k
  bx8 v = ((bx8*)vT)[i];
  const float* c = cs + (size_t)b * S_ + k;
#pragma unroll
  for (int j = 0; j < 8; j++) v[j] = (__bf16)((float)v[j] / c[j]);
  ((bx8*)vT)[i] = v;
}

// ---------------------------------------------------------------- launch
extern "C" void kernel_launch(void* const* d_in, const int* in_sizes, int n_in,
                              void* d_out, int out_size, void* d_ws, size_t ws_size,
                              hipStream_t stream) {
  const float* seq1 = (const float*)d_in[0];
  const float* seq2 = (const float*)d_in[1];
  const int*   mask = (const int*)d_in[2];
  const float* Wq   = (const float*)d_in[3];
  const float* Wk   = (const float*)d_in[4];
  const float* Wv   = (const float*)d_in[5];

  char* ws = (char*)d_ws;
  __bf16* A1  = (__bf16*)(ws + WS_A1);
  __bf16* A2  = (__bf16*)(ws + WS_A2);
  __bf16* Pu  = (__bf16*)(ws + WS_PU);
  __bf16* WQb = (__bf16*)(ws + WS_WQ);
  u64*    bm  = (u64*)(ws + WS_BM);      // aliases WQb after Q-proj
  __bf16* WKb = (__bf16*)(ws + WS_WK);   // [Wk;Wv] contiguous 2048x1024
  __bf16* WVb = (__bf16*)(ws + WS_WV);
  __bf16* qb  = (__bf16*)(ws + WS_Q);
  __bf16* kb  = (__bf16*)(ws + WS_K);
  __bf16* vTb = (__bf16*)(ws + WS_VT);
  float*  cs  = (float*)(ws + WS_CS);

  (void)hipFuncSetAttribute((const void*)gemm256<EP_BF16>,
      hipFuncAttributeMaxDynamicSharedMemorySize, 131072);
  (void)hipFuncSetAttribute((const void*)gemm256<EP_KV>,
      hipFuncAttributeMaxDynamicSharedMemorySize, 131072);
  (void)hipFuncSetAttribute((const void*)gemm256<EP_EXP>,
      hipFuncAttributeMaxDynamicSharedMemorySize, 131072);
  (void)hipFuncSetAttribute((const void*)gemm256<EP_F32>,
      hipFuncAttributeMaxDynamicSharedMemorySize, 131072);

  // fp32 -> bf16 conversions
  cvt_f32_bf16<<<4096, 256, 0, stream>>>(seq1, A1);
  cvt_f32_bf16<<<4096, 256, 0, stream>>>(seq2, A2);
  cvt_f32_bf16<<<512, 256, 0, stream>>>(Wq, WQb);
  cvt_f32_bf16<<<512, 256, 0, stream>>>(Wk, WKb);
  cvt_f32_bf16<<<512, 256, 0, stream>>>(Wv, WVb);

  // q = seq1 @ Wq^T   (M=8192, N=1024)
  gemm256<EP_BF16><<<dim3(DH / 256, (B_ * S_) / 256, 1), 512, 131072, stream>>>(
      A1, WQb, qb, nullptr, nullptr, DH, DIN, 0, 0);
  // [k | vT] = seq2 @ [Wk;Wv]^T  (M=8192, N=2048, split epilogue)
  gemm256<EP_KV><<<dim3(2048 / 256, (B_ * S_) / 256, 1), 512, 131072, stream>>>(
      A2, WKb, kb, vTb, nullptr, 2048, DIN, 0, 0);

  // pack mask to bits (overwrites Wq region, dead after Q-proj)
  pack_mask<<<8192, 256, 0, stream>>>(mask, bm);
  hipMemsetAsync(ws + WS_CS, 0, (size_t)B_ * S_ * sizeof(float), stream);

  // Pu[b,q,k] = mask ? 1 : exp(q.k/32); fused fp32 column-sum atomics into cs
  gemm256<EP_EXP><<<dim3(S_ / 256, S_ / 256, B_), 512, 131072, stream>>>(
      qb, kb, Pu, cs, bm, S_, DH, (long)S_ * DH, (long)S_ * DH);

  // fold 1/colsum into vT
  scale_vt<<<(B_ * DH * S_ / 8) / 256, 256, 0, stream>>>(vTb, cs);

  // out[b,q,h] = sum_k Pu[b,q,k] * vT'[b,h,k]   (M=2048, N=1024, K=2048)
  gemm256<EP_F32><<<dim3(DH / 256, S_ / 256, B_), 512, 131072, stream>>>(
      Pu, vTb, (float*)d_out, nullptr, nullptr, DH, S_, (long)S_ * S_, (long)DH * S_);
}